// Round 2
// baseline (539.785 us; speedup 1.0000x reference)
//
#include <hip/hip_runtime.h>
#include <math.h>

#define TT 2048
#define NN 8192
#define HH 128
#define NB 1024    // grid blocks: 4 per CU on 256 CUs -> co-resident by construction
#define BS 256

typedef float f4 __attribute__((ext_vector_type(4)));

// ---------------------------------------------------------------------------
// Device-scope grid barrier: single monotone counter, absolute targets.
// Counter is zeroed by init_kernel each launch (workspace is poisoned between
// iterations, so we must not trust its contents). clock64 timeout => a
// co-residency failure produces a wrong-answer FAIL, never a hang.
// ---------------------------------------------------------------------------
__device__ __forceinline__ void grid_barrier(unsigned* ctr, unsigned target) {
    __syncthreads();
    if (threadIdx.x == 0) {
        __threadfence();                       // release: make phase writes visible device-wide
        atomicAdd(ctr, 1u);                    // device-scope by default
        const long long t0 = clock64();
        while (__hip_atomic_load(ctr, __ATOMIC_RELAXED, __HIP_MEMORY_SCOPE_AGENT) < target) {
            __builtin_amdgcn_s_sleep(2);
            if (clock64() - t0 > 200000000LL) break;   // ~80 ms failsafe
        }
        __threadfence();                       // acquire: invalidate stale cached data
    }
    __syncthreads();
}

__global__ void init_kernel(unsigned* ctr) { *ctr = 0u; }

__device__ __forceinline__ void mm4(const float* __restrict__ A,
                                    const float* __restrict__ B,
                                    float* __restrict__ C) {
    #pragma unroll
    for (int i = 0; i < 4; ++i) {
        #pragma unroll
        for (int j = 0; j < 4; ++j) {
            float s = 0.0f;
            #pragma unroll
            for (int k = 0; k < 4; ++k) s = fmaf(A[i * 4 + k], B[k * 4 + j], s);
            C[i * 4 + j] = s;
        }
    }
}

// ---------------------------------------------------------------------------
// Fused pipeline: MLP -> cumsum -> expm -> apply, one dispatch.
// 1024 blocks x 256 threads, __launch_bounds__(256,4) caps VGPR at 128 so all
// 1024 blocks are simultaneously resident (4 blocks/CU x 256 CUs).
// ---------------------------------------------------------------------------
__global__ __launch_bounds__(BS, 4) void fused_kernel(
    const float* __restrict__ t_arr, const float* __restrict__ M0,
    const float* __restrict__ W1, const float* __restrict__ b1,
    const float* __restrict__ W2, const float* __restrict__ b2,
    const float* __restrict__ W3, const float* __restrict__ b3,
    const float* __restrict__ x, float* __restrict__ out,
    float* __restrict__ A_t, float* __restrict__ Asum,
    float* __restrict__ E, unsigned* ctr)
{
    // ---- Phase 1: per-timestep MLP (2 timesteps per block) ----------------
    {
        const int tloc = threadIdx.x >> 7;           // 0..1
        const int j    = threadIdx.x & 127;          // 0..127
        const int t    = (blockIdx.x << 1) + tloc;   // 0..2047
        __shared__ float h1[2][HH];
        __shared__ float h2[2][HH];

        const float t_cur  = t_arr[t];
        const float t_prev = (t > 0) ? t_arr[t - 1] : 0.0f;
        const float dt = t_cur - t_prev;
        const float ta = 0.5f * (t_cur + t_prev);

        h1[tloc][j] = tanhf(fmaf(ta, W1[j], b1[j]));
        __syncthreads();

        float acc = b2[j];
        #pragma unroll 8
        for (int i = 0; i < HH; ++i) acc = fmaf(h1[tloc][i], W2[i * HH + j], acc);
        h2[tloc][j] = tanhf(acc);
        __syncthreads();

        if (j < 16) {
            float a = b3[j];
            #pragma unroll 8
            for (int i = 0; i < HH; ++i) a = fmaf(h2[tloc][i], W3[i * 16 + j], a);
            a = (a + M0[j]) * dt;
            A_t[j * TT + t] = a;    // transposed: contiguous per-element sequences
        }
    }
    grid_barrier(ctr, NB);

    // ---- Phase 2: cumsum over t of 16 element-sequences (block 0 only) ----
    // 4 waves; wave w scans elements e = 4w..4w+3 sequentially. Lane owns a
    // 32-step chunk: chunk-sum -> __shfl_up wave scan -> re-emit.
    if (blockIdx.x == 0) {
        const int w    = threadIdx.x >> 6;   // 0..3
        const int lane = threadIdx.x & 63;   // 0..63
        for (int r = 0; r < 4; ++r) {
            const int e = (w << 2) + r;
            const float4* src = (const float4*)(A_t + e * TT + lane * 32);
            float4 v[8];
            float s = 0.0f;
            #pragma unroll
            for (int i = 0; i < 8; ++i) {
                v[i] = src[i];
                s += v[i].x + v[i].y + v[i].z + v[i].w;
            }
            float sc = s;
            #pragma unroll
            for (int d = 1; d < 64; d <<= 1) {
                const float up = __shfl_up(sc, d, 64);
                if (lane >= d) sc += up;
            }
            const float ex = __shfl_up(sc, 1, 64);
            float run = (lane == 0) ? 0.0f : ex;
            const int t0 = lane * 32;
            #pragma unroll
            for (int i = 0; i < 8; ++i) {
                run += v[i].x; Asum[(t0 + 4 * i + 0) * 16 + e] = run;
                run += v[i].y; Asum[(t0 + 4 * i + 1) * 16 + e] = run;
                run += v[i].z; Asum[(t0 + 4 * i + 2) * 16 + e] = run;
                run += v[i].w; Asum[(t0 + 4 * i + 3) * 16 + e] = run;
            }
        }
    }
    grid_barrier(ctr, 2 * NB);

    // ---- Phase 3: batched 4x4 expm (blocks 0..7, one thread per t) --------
    {
        const int t = blockIdx.x * BS + threadIdx.x;
        if (t < TT) {
            float M[16];
            const float4* src = (const float4*)(Asum + t * 16);
            #pragma unroll
            for (int r = 0; r < 4; ++r) {
                float4 v = src[r];
                M[r*4+0] = v.x; M[r*4+1] = v.y; M[r*4+2] = v.z; M[r*4+3] = v.w;
            }
            float nrm = 0.0f;
            #pragma unroll
            for (int i = 0; i < 4; ++i) {
                float rs = fabsf(M[i*4+0]) + fabsf(M[i*4+1]) + fabsf(M[i*4+2]) + fabsf(M[i*4+3]);
                nrm = fmaxf(nrm, rs);
            }
            int k = 0;
            while (nrm > 0.5f && k < 40) { nrm *= 0.5f; ++k; }
            const float sc = ldexpf(1.0f, -k);
            #pragma unroll
            for (int i = 0; i < 16; ++i) M[i] *= sc;

            float R[16], P[16], Q[16];
            #pragma unroll
            for (int i = 0; i < 16; ++i) { P[i] = M[i]; R[i] = M[i]; }
            R[0] += 1.0f; R[5] += 1.0f; R[10] += 1.0f; R[15] += 1.0f;
            for (int n = 2; n <= 12; ++n) {
                mm4(P, M, Q);
                const float inv = 1.0f / (float)n;
                #pragma unroll
                for (int i = 0; i < 16; ++i) { P[i] = Q[i] * inv; R[i] += P[i]; }
            }
            for (int s = 0; s < k; ++s) {
                mm4(R, R, Q);
                #pragma unroll
                for (int i = 0; i < 16; ++i) R[i] = Q[i];
            }
            float4* dst = (float4*)(E + t * 16);
            #pragma unroll
            for (int r = 0; r < 4; ++r)
                dst[r] = make_float4(R[r*4+0], R[r*4+1], R[r*4+2], R[r*4+3]);
        }
    }
    grid_barrier(ctr, 3 * NB);

    // ---- Phase 4: out[t,n,:] = E[t] @ x[n]  (2 timesteps per block) -------
    {
        const f4* xs = (const f4*)x;
        #pragma unroll
        for (int tl = 0; tl < 2; ++tl) {
            const int t = (blockIdx.x << 1) + tl;
            const f4* Ev = (const f4*)(E + t * 16);
            const f4 e0 = Ev[0], e1 = Ev[1], e2 = Ev[2], e3 = Ev[3];
            f4* os = (f4*)out + (size_t)t * NN;
            for (int n = threadIdx.x; n < NN; n += BS) {
                const f4 xv = xs[n];
                f4 o;
                o.x = fmaf(e0.x, xv.x, fmaf(e0.y, xv.y, fmaf(e0.z, xv.z, e0.w * xv.w)));
                o.y = fmaf(e1.x, xv.x, fmaf(e1.y, xv.y, fmaf(e1.z, xv.z, e1.w * xv.w)));
                o.z = fmaf(e2.x, xv.x, fmaf(e2.y, xv.y, fmaf(e2.z, xv.z, e2.w * xv.w)));
                o.w = fmaf(e3.x, xv.x, fmaf(e3.y, xv.y, fmaf(e3.z, xv.z, e3.w * xv.w)));
                os[n] = o;    // plain stores: match the 6.3 TB/s fill pattern
            }
        }
    }
}

// ---------------------------------------------------------------------------
extern "C" void kernel_launch(void* const* d_in, const int* in_sizes, int n_in,
                              void* d_out, int out_size, void* d_ws, size_t ws_size,
                              hipStream_t stream) {
    const float* x  = (const float*)d_in[0];   // (N, D)
    const float* t  = (const float*)d_in[1];   // (T,)
    const float* M0 = (const float*)d_in[2];   // (D, D) zeros
    const float* W1 = (const float*)d_in[3];   // (1, H)
    const float* b1 = (const float*)d_in[4];   // (H,)
    const float* W2 = (const float*)d_in[5];   // (H, H)
    const float* b2 = (const float*)d_in[6];   // (H,)
    const float* W3 = (const float*)d_in[7];   // (H, 16)
    const float* b3 = (const float*)d_in[8];   // (16,)
    float* out = (float*)d_out;                // (T, N, D) f32

    float* A_t  = (float*)d_ws;                // 16*T floats (transposed)
    float* Asum = A_t  + 16 * TT;              // 16*T floats, (T,16)
    float* E    = Asum + 16 * TT;              // 16*T floats, (T,16)
    unsigned* ctr = (unsigned*)(E + 16 * TT);  // barrier counter (zeroed per launch)

    init_kernel<<<1, 1, 0, stream>>>(ctr);
    fused_kernel<<<NB, BS, 0, stream>>>(t, M0, W1, b1, W2, b2, W3, b3,
                                        x, out, A_t, Asum, E, ctr);
}

// Round 3
// 313.130 us; speedup vs baseline: 1.7238x; 1.7238x over previous
//
#include <hip/hip_runtime.h>
#include <math.h>

#define TT 2048
#define NN 8192
#define HH 128

typedef float f4 __attribute__((ext_vector_type(4)));

// ---------------------------------------------------------------------------
// Stage 1: per-timestep MLP -> A, stored TRANSPOSED: A_t[e*TT + t], e in [0,16)
// One block per timestep, HH=128 threads.
// ---------------------------------------------------------------------------
__global__ void mlp_kernel(const float* __restrict__ t_arr,
                           const float* __restrict__ M0,
                           const float* __restrict__ W1, const float* __restrict__ b1,
                           const float* __restrict__ W2, const float* __restrict__ b2,
                           const float* __restrict__ W3, const float* __restrict__ b3,
                           float* __restrict__ A_t) {
    const int t = blockIdx.x;
    const int j = threadIdx.x;
    __shared__ float h1[HH];
    __shared__ float h2[HH];

    const float t_cur  = t_arr[t];
    const float t_prev = (t > 0) ? t_arr[t - 1] : 0.0f;
    const float dt = t_cur - t_prev;
    const float ta = 0.5f * (t_cur + t_prev);

    h1[j] = tanhf(fmaf(ta, W1[j], b1[j]));
    __syncthreads();

    float acc = b2[j];
    #pragma unroll 8
    for (int i = 0; i < HH; ++i) acc = fmaf(h1[i], W2[i * HH + j], acc);
    h2[j] = tanhf(acc);
    __syncthreads();

    if (j < 16) {
        float a = b3[j];
        #pragma unroll 8
        for (int i = 0; i < HH; ++i) a = fmaf(h2[i], W3[i * 16 + j], a);
        a = (a + M0[j]) * dt;
        A_t[j * TT + t] = a;   // transposed layout for contiguous scan loads
    }
}

// ---------------------------------------------------------------------------
// Stage 2: cumsum over t of the 16 element-sequences.
// Single block, 1024 threads = 16 waves. Wave w owns element e=w; lanes own
// 64 chunks of 32 steps. Chunk-sum -> __shfl_up wave scan -> re-emit.
// Output layout: Asum[t*16 + e].
// ---------------------------------------------------------------------------
__global__ __launch_bounds__(1024) void scan_kernel(const float* __restrict__ A_t,
                                                    float* __restrict__ Asum) {
    const int tid = threadIdx.x;
    const int e = tid >> 6;        // 0..15  (== wave id)
    const int c = tid & 63;        // 0..63  (== lane id)
    const float4* src = (const float4*)(A_t + e * TT + c * 32);

    float4 v[8];
    float s = 0.0f;
    #pragma unroll
    for (int i = 0; i < 8; ++i) {
        v[i] = src[i];
        s += v[i].x + v[i].y + v[i].z + v[i].w;
    }

    float sc = s;
    #pragma unroll
    for (int d = 1; d < 64; d <<= 1) {
        const float up = __shfl_up(sc, d, 64);
        if (c >= d) sc += up;
    }
    const float ex = __shfl_up(sc, 1, 64);
    float run = (c == 0) ? 0.0f : ex;

    const int t0 = c * 32;
    #pragma unroll
    for (int i = 0; i < 8; ++i) {
        run += v[i].x; Asum[(t0 + 4 * i + 0) * 16 + e] = run;
        run += v[i].y; Asum[(t0 + 4 * i + 1) * 16 + e] = run;
        run += v[i].z; Asum[(t0 + 4 * i + 2) * 16 + e] = run;
        run += v[i].w; Asum[(t0 + 4 * i + 3) * 16 + e] = run;
    }
}

// ---------------------------------------------------------------------------
// Stage 3: batched 4x4 expm via scaling-and-squaring + Taylor(12).
// One thread per timestep; 32 blocks x 64 threads.
// ---------------------------------------------------------------------------
__device__ __forceinline__ void mm4(const float* __restrict__ A,
                                    const float* __restrict__ B,
                                    float* __restrict__ C) {
    #pragma unroll
    for (int i = 0; i < 4; ++i) {
        #pragma unroll
        for (int j = 0; j < 4; ++j) {
            float s = 0.0f;
            #pragma unroll
            for (int k = 0; k < 4; ++k) s = fmaf(A[i * 4 + k], B[k * 4 + j], s);
            C[i * 4 + j] = s;
        }
    }
}

__global__ __launch_bounds__(64) void expm_kernel(const float* __restrict__ Asum,
                                                  float* __restrict__ E) {
    const int t = blockIdx.x * blockDim.x + threadIdx.x;
    if (t >= TT) return;

    float M[16];
    const float4* src = (const float4*)(Asum + t * 16);
    #pragma unroll
    for (int r = 0; r < 4; ++r) {
        float4 v = src[r];
        M[r * 4 + 0] = v.x; M[r * 4 + 1] = v.y; M[r * 4 + 2] = v.z; M[r * 4 + 3] = v.w;
    }

    float nrm = 0.0f;
    #pragma unroll
    for (int i = 0; i < 4; ++i) {
        float rs = fabsf(M[i*4+0]) + fabsf(M[i*4+1]) + fabsf(M[i*4+2]) + fabsf(M[i*4+3]);
        nrm = fmaxf(nrm, rs);
    }
    int k = 0;
    while (nrm > 0.5f && k < 40) { nrm *= 0.5f; ++k; }
    const float sc = ldexpf(1.0f, -k);
    #pragma unroll
    for (int i = 0; i < 16; ++i) M[i] *= sc;

    float R[16], P[16], Q[16];
    #pragma unroll
    for (int i = 0; i < 16; ++i) { P[i] = M[i]; R[i] = M[i]; }
    R[0] += 1.0f; R[5] += 1.0f; R[10] += 1.0f; R[15] += 1.0f;
    for (int n = 2; n <= 12; ++n) {
        mm4(P, M, Q);
        const float inv = 1.0f / (float)n;
        #pragma unroll
        for (int i = 0; i < 16; ++i) { P[i] = Q[i] * inv; R[i] += P[i]; }
    }
    for (int s = 0; s < k; ++s) {
        mm4(R, R, Q);
        #pragma unroll
        for (int i = 0; i < 16; ++i) R[i] = Q[i];
    }

    float4* dst = (float4*)(E + t * 16);
    #pragma unroll
    for (int r = 0; r < 4; ++r)
        dst[r] = make_float4(R[r*4+0], R[r*4+1], R[r*4+2], R[r*4+3]);
}

// ---------------------------------------------------------------------------
// Stage 4: out[t,n,:] = E[t] @ x[n].  256 MB store stream.
// grid (2, TT) = 4096 blocks x 256 threads; E[t] in registers (uniform loads),
// 16 independent float4 load/store iterations per thread.
// PLAIN stores (the 6.33 TB/s fillBuffer path) — no NT, no LDS, no barrier.
// ---------------------------------------------------------------------------
__global__ __launch_bounds__(256) void apply_kernel(const float* __restrict__ E,
                                                    const float* __restrict__ x,
                                                    float* __restrict__ out) {
    const int t = blockIdx.y;
    const int nbase = blockIdx.x * (NN / 2);

    const f4* Ev = (const f4*)(E + t * 16);
    const f4 e0 = Ev[0], e1 = Ev[1], e2 = Ev[2], e3 = Ev[3];

    const f4* xs = (const f4*)x + nbase;
    f4* os = (f4*)out + (size_t)t * NN + nbase;

    #pragma unroll 4
    for (int n = threadIdx.x; n < NN / 2; n += 256) {
        const f4 xv = xs[n];
        f4 o;
        o.x = fmaf(e0.x, xv.x, fmaf(e0.y, xv.y, fmaf(e0.z, xv.z, e0.w * xv.w)));
        o.y = fmaf(e1.x, xv.x, fmaf(e1.y, xv.y, fmaf(e1.z, xv.z, e1.w * xv.w)));
        o.z = fmaf(e2.x, xv.x, fmaf(e2.y, xv.y, fmaf(e2.z, xv.z, e2.w * xv.w)));
        o.w = fmaf(e3.x, xv.x, fmaf(e3.y, xv.y, fmaf(e3.z, xv.z, e3.w * xv.w)));
        os[n] = o;
    }
}

// ---------------------------------------------------------------------------
extern "C" void kernel_launch(void* const* d_in, const int* in_sizes, int n_in,
                              void* d_out, int out_size, void* d_ws, size_t ws_size,
                              hipStream_t stream) {
    const float* x  = (const float*)d_in[0];   // (N, D)
    const float* t  = (const float*)d_in[1];   // (T,)
    const float* M0 = (const float*)d_in[2];   // (D, D) zeros
    const float* W1 = (const float*)d_in[3];   // (1, H)
    const float* b1 = (const float*)d_in[4];   // (H,)
    const float* W2 = (const float*)d_in[5];   // (H, H)
    const float* b2 = (const float*)d_in[6];   // (H,)
    const float* W3 = (const float*)d_in[7];   // (H, 16)
    const float* b3 = (const float*)d_in[8];   // (16,)
    float* out = (float*)d_out;                // (T, N, D) f32

    float* A_t  = (float*)d_ws;                // 16*T floats (transposed)
    float* Asum = A_t  + 16 * TT;              // 16*T floats, (T,16)
    float* E    = Asum + 16 * TT;              // 16*T floats, (T,16)

    mlp_kernel<<<TT, HH, 0, stream>>>(t, M0, W1, b1, W2, b2, W3, b3, A_t);
    scan_kernel<<<1, 1024, 0, stream>>>(A_t, Asum);
    expm_kernel<<<TT / 64, 64, 0, stream>>>(Asum, E);
    apply_kernel<<<dim3(2, TT), 256, 0, stream>>>(E, x, out);
}